// Round 1
// baseline (153386.255 us; speedup 1.0000x reference)
//
#include <hip/hip_runtime.h>
#include <hip/hip_cooperative_groups.h>
#include <cstdint>
#include <cstddef>

namespace cg = cooperative_groups;

#define T_STEPS 1000
#define B_SZ    128
#define F_IN    72
#define NU      512
#define NC      14
#define K0TOT   592   /* 80 (x padded 72->80) + 512 (h0) */
#define K1TOT   1024  /* 512 (h0n via G1) + 512 (h1 via U1) */

// ---- workspace layout (float offsets) ----
#define OFF_BP0   0
#define SZ_BP0    (128*K0TOT*16)
#define OFF_BP1   (OFF_BP0 + SZ_BP0)
#define SZ_BP1    (128*K1TOT*16)
#define OFF_S1P   (OFF_BP1 + SZ_BP1)
#define OFF_ZB1P  (OFF_S1P + 2048)
#define OFF_B0P   (OFF_ZB1P + 2048)
#define OFF_STATE (OFF_B0P + 2048)      /* h0buf[2], c0, h1, c1 : 5*65536 */
#define OFF_MU    (OFF_STATE + 5*65536)
#define OFF_RSTD  (OFF_MU + 128)

// ---------------- weight packing ----------------
// Bp0[ntile][k 0..591][16]; c = u*4+g ; zcol = ntile*4 + u + 512*g
__global__ void pack0_kernel(const float* __restrict__ w0, const float* __restrict__ u0,
                             float* __restrict__ bp0)
{
    int blk = blockIdx.x;            // 128 ntiles * 10 kchunks
    int ntile = blk / 10, kc = blk % 10;
    int k0 = kc * 64;
#pragma unroll
    for (int p = 0; p < 4; p++) {
        int e = threadIdx.x + p * 256;
        int kr = e >> 4, c = e & 15;
        int k = k0 + kr;
        if (k < K0TOT) {
            int u = c >> 2, g = c & 3;
            int zcol = ntile * 4 + u + 512 * g;
            float v;
            if (k < F_IN)      v = w0[k * 2048 + zcol];
            else if (k < 80)   v = 0.f;
            else               v = u0[(k - 80) * 2048 + zcol];
            bp0[((size_t)ntile * K0TOT + k) * 16 + c] = v;
        }
    }
}

// Bp1[ntile][k 0..1023][16]: k<512 -> gamma[k]*W1[k][zcol], else U1[k-512][zcol]
__global__ void pack1_kernel(const float* __restrict__ w1, const float* __restrict__ u1,
                             const float* __restrict__ gamma, float* __restrict__ bp1)
{
    int blk = blockIdx.x;            // 128 * 16
    int ntile = blk >> 4, kc = blk & 15;
    int k0 = kc * 64;
#pragma unroll
    for (int p = 0; p < 4; p++) {
        int e = threadIdx.x + p * 256;
        int kr = e >> 4, c = e & 15;
        int k = k0 + kr;
        int u = c >> 2, g = c & 3;
        int zcol = ntile * 4 + u + 512 * g;
        float v = (k < NU) ? gamma[k] * w1[k * 2048 + zcol]
                           : u1[(k - NU) * 2048 + zcol];
        bp1[((size_t)ntile * K1TOT + k) * 16 + c] = v;
    }
}

// s1p[pc] = sum_k gamma[k]*W1[k][zcol]; zb1p[pc] = b1 + sum_k beta[k]*W1[k][zcol]; b0p packed
__global__ void sums_kernel(const float* __restrict__ w1, const float* __restrict__ gamma,
                            const float* __restrict__ beta, const float* __restrict__ b0,
                            const float* __restrict__ b1,
                            float* __restrict__ s1p, float* __restrict__ zb1p,
                            float* __restrict__ b0p)
{
    int zcol = blockIdx.x * 256 + threadIdx.x;   // 8 blocks * 256
    float gs = 0.f, bs = 0.f;
    for (int k = 0; k < NU; k++) {
        float w = w1[k * 2048 + zcol];
        gs += gamma[k] * w;
        bs += beta[k] * w;
    }
    int g = zcol >> 9, r = zcol & 511, nt = r >> 2, u = r & 3;
    int pc = nt * 16 + u * 4 + g;
    s1p[pc]  = gs;
    zb1p[pc] = b1[zcol] + bs;
    b0p[pc]  = b0[zcol];
}

// ---------------- main persistent kernel ----------------
__device__ __forceinline__ float sigf(float x)     { return 1.f / (1.f + __expf(-x)); }
__device__ __forceinline__ float tanhfast(float x) { return 2.f / (1.f + __expf(-2.f * x)) - 1.f; }

template <int KC>
__device__ __forceinline__ void gemm_chunk(const float* __restrict__ SM, int abase, int bl,
                                           const float* __restrict__ bp, float acc[8])
{
#pragma unroll
    for (int k = 0; k < KC; k++) {
        float a = SM[abase + k * 65 + bl];
        float4 b0 = *(const float4*)(bp + k * 16);
        float4 b1 = *(const float4*)(bp + k * 16 + 4);
        acc[0] = fmaf(a, b0.x, acc[0]); acc[1] = fmaf(a, b0.y, acc[1]);
        acc[2] = fmaf(a, b0.z, acc[2]); acc[3] = fmaf(a, b0.w, acc[3]);
        acc[4] = fmaf(a, b1.x, acc[4]); acc[5] = fmaf(a, b1.y, acc[5]);
        acc[6] = fmaf(a, b1.z, acc[6]); acc[7] = fmaf(a, b1.w, acc[7]);
    }
}

// stage 64 rows x KC cols of src (row stride given) into SM transposed [k][row], stride 65
template <int KC>
__device__ __forceinline__ void stage_chunk(float* __restrict__ SM, int abase, int gtid,
                                            const float* __restrict__ src, int rowstride)
{
#pragma unroll
    for (int i = 0; i < (64 * KC) / 128; i++) {
        int e = gtid + i * 128;
        int row = e / KC;
        int kk = e - row * KC;
        SM[abase + kk * 65 + row] = src[row * rowstride + kk];
    }
}

__device__ __forceinline__ void stage_x(float* __restrict__ SM, int abase, int gtid,
                                        const float* __restrict__ src, int ks)
{
#pragma unroll
    for (int i = 0; i < 10; i++) {
        int e = gtid + i * 128;
        int row = e / 20;
        int kk = e - row * 20;
        int kg = ks * 20 + kk;
        float v = (kg < F_IN) ? src[row * 72000 + kg] : 0.f;
        SM[abase + kk * 65 + row] = v;
    }
}

__device__ void ypass(const float* __restrict__ h1, const float* __restrict__ wf,
                      const float* __restrict__ bf, float* __restrict__ out,
                      int b, int tw, int lane)
{
    const float* hr = h1 + b * NU;
    float hv[8];
#pragma unroll
    for (int i = 0; i < 8; i++) hv[i] = hr[lane * 8 + i];
    float z[NC];
#pragma unroll
    for (int c = 0; c < NC; c++) {
        float a = 0.f;
#pragma unroll
        for (int i = 0; i < 8; i++) a = fmaf(hv[i], wf[(lane * 8 + i) * NC + c], a);
        z[c] = a;
    }
#pragma unroll
    for (int off = 32; off > 0; off >>= 1) {
#pragma unroll
        for (int c = 0; c < NC; c++) z[c] += __shfl_xor(z[c], off);
    }
    if (lane == 0) {
        float m = -1e30f;
#pragma unroll
        for (int c = 0; c < NC; c++) { z[c] += bf[c]; m = fmaxf(m, z[c]); }
        float s = 0.f, e[NC];
#pragma unroll
        for (int c = 0; c < NC; c++) { e[c] = __expf(z[c] - m); s += e[c]; }
        float inv = 1.f / s;
        float* o = out + ((size_t)b * T_STEPS + tw) * NC;
#pragma unroll
        for (int c = 0; c < NC; c++) o[c] = e[c] * inv;
    }
}

__global__ __launch_bounds__(512, 1)
void lstm_main(const float* __restrict__ x,
               const float* __restrict__ wf, const float* __restrict__ bf,
               float* __restrict__ ws, float* __restrict__ out)
{
    cg::grid_group grid = cg::this_grid();
    __shared__ float SM[8320];   // 4 groups x [32][65] A-tiles; reused as zex after K-loops

    const float* __restrict__ bp0  = ws + OFF_BP0;
    const float* __restrict__ bp1  = ws + OFF_BP1;
    const float* __restrict__ s1p  = ws + OFF_S1P;
    const float* __restrict__ zb1p = ws + OFF_ZB1P;
    const float* __restrict__ b0p  = ws + OFF_B0P;
    float* __restrict__ state = ws + OFF_STATE;
    float* __restrict__ h0buf = state;               // 2*65536
    float* __restrict__ c0    = state + 2 * 65536;
    float* __restrict__ h1    = state + 3 * 65536;
    float* __restrict__ c1    = state + 4 * 65536;
    float* __restrict__ muv   = ws + OFF_MU;
    float* __restrict__ rsv   = ws + OFF_RSTD;

    const int tid  = threadIdx.x;
    const int bl   = tid & 63;             // batch row within tile
    const int ks   = (tid >> 6) & 3;       // K-split group
    const int ch   = tid >> 8;             // column half (8 cols each)
    const int gtid = bl + ((tid >> 8) << 6);  // 0..127 within ks-group
    const int abase = ks * 2080;           // 32*65 per group
    const int blk = blockIdx.x;
    const int mtile = blk & 1, ntile = blk >> 1;
    const int rb = mtile * 64;

    // zero recurrent state (ws is poisoned before timing; must re-init every launch)
    for (int i = blk * 512 + tid; i < 5 * 65536; i += 256 * 512) state[i] = 0.f;
    grid.sync();

#pragma unroll 1
    for (int t = 0; t < T_STEPS; t++) {
        float* __restrict__ h0cur = h0buf + (t & 1) * 65536;
        const float* __restrict__ h0prev = h0buf + ((t & 1) ^ 1) * 65536;

        // ================= PHASE A: z0 = [x_t | h0] @ [W0;U0] -> h0cur, c0 ===========
        float acc[8] = {0.f, 0.f, 0.f, 0.f, 0.f, 0.f, 0.f, 0.f};
        const float* bpA = bp0 + ((size_t)ntile * K0TOT) * 16 + ch * 8;

        stage_x(SM, abase, gtid, x + (size_t)rb * 72000 + t * 72, ks);
        __syncthreads();
        gemm_chunk<20>(SM, abase, bl, bpA + (ks * 20) * 16, acc);
        __syncthreads();
#pragma unroll 1
        for (int cc = 0; cc < 4; cc++) {
            stage_chunk<32>(SM, abase, gtid, h0prev + rb * NU + ks * 128 + cc * 32, NU);
            __syncthreads();
            gemm_chunk<32>(SM, abase, bl, bpA + (80 + ks * 128 + cc * 32) * 16, acc);
            __syncthreads();
        }
#pragma unroll
        for (int i = 0; i < 8; i++) SM[ks * 1024 + (ch * 8 + i) * 64 + bl] = acc[i];
        __syncthreads();
        if (tid < 256) {
            int b = tid & 63, u = tid >> 6;
            int pcb = ntile * 16 + u * 4;
            float z[4];
#pragma unroll
            for (int g = 0; g < 4; g++) {
                int c = u * 4 + g;
                z[g] = SM[c * 64 + b] + SM[1024 + c * 64 + b] + SM[2048 + c * 64 + b] +
                       SM[3072 + c * 64 + b] + b0p[pcb + g];
            }
            int gb = rb + b, j = ntile * 4 + u, idx = gb * NU + j;
            float ig = sigf(z[0]), fg = sigf(z[1]), gg = tanhfast(z[2]), og = sigf(z[3]);
            float cn = fg * c0[idx] + ig * gg;
            c0[idx] = cn;
            h0cur[idx] = og * tanhfast(cn);
        }
        grid.sync();   // -------- SYNC 1: h0cur visible everywhere --------

        // LN stats (blocks 0..127, wave 0), in parallel with phase-B staging elsewhere
        if (blk < 128 && tid < 64) {
            const float* hr = h0cur + blk * NU;
            float s = 0.f, q = 0.f;
#pragma unroll
            for (int i = 0; i < 8; i++) { float v = hr[tid * 8 + i]; s += v; q += v * v; }
#pragma unroll
            for (int off = 32; off > 0; off >>= 1) { s += __shfl_xor(s, off); q += __shfl_xor(q, off); }
            if (tid == 0) {
                float m = s * (1.f / 512.f);
                float var = q * (1.f / 512.f) - m * m;
                muv[blk] = m;
                rsv[blk] = rsqrtf(var + 1e-3f);
            }
        }
        // softmax head for step t-1 (blocks 128..255, wave 0) — h1 still holds h1(t-1)
        if (blk >= 128 && tid < 64 && t > 0) {
            ypass(h1, wf, bf, out, blk - 128, t - 1, tid);
        }

        // ============ PHASE B: z1 = h0n@G1 + h1@U1 (LN folded to epilogue) ==========
        float accG[8] = {0.f, 0.f, 0.f, 0.f, 0.f, 0.f, 0.f, 0.f};
        float accU[8] = {0.f, 0.f, 0.f, 0.f, 0.f, 0.f, 0.f, 0.f};
        const float* bpB = bp1 + ((size_t)ntile * K1TOT) * 16 + ch * 8;
#pragma unroll 1
        for (int cc = 0; cc < 4; cc++) {
            stage_chunk<32>(SM, abase, gtid, h0cur + rb * NU + ks * 128 + cc * 32, NU);
            __syncthreads();
            gemm_chunk<32>(SM, abase, bl, bpB + (ks * 128 + cc * 32) * 16, accG);
            __syncthreads();
        }
#pragma unroll 1
        for (int cc = 0; cc < 4; cc++) {
            stage_chunk<32>(SM, abase, gtid, h1 + rb * NU + ks * 128 + cc * 32, NU);
            __syncthreads();
            gemm_chunk<32>(SM, abase, bl, bpB + (512 + ks * 128 + cc * 32) * 16, accU);
            __syncthreads();
        }
#pragma unroll
        for (int i = 0; i < 8; i++) {
            SM[ks * 1024 + (ch * 8 + i) * 64 + bl]        = accG[i];
            SM[4096 + ks * 1024 + (ch * 8 + i) * 64 + bl] = accU[i];
        }
        __syncthreads();
        grid.sync();   // -------- SYNC 2: mu/rstd visible; all h0/h1 reads done --------
        if (tid < 256) {
            int b = tid & 63, u = tid >> 6;
            int gb = rb + b;
            float rs = rsv[gb], m = muv[gb];
            int pcb = ntile * 16 + u * 4;
            float z[4];
#pragma unroll
            for (int g = 0; g < 4; g++) {
                int c = u * 4 + g;
                float zG = SM[c * 64 + b] + SM[1024 + c * 64 + b] + SM[2048 + c * 64 + b] + SM[3072 + c * 64 + b];
                float zU = SM[4096 + c * 64 + b] + SM[5120 + c * 64 + b] + SM[6144 + c * 64 + b] + SM[7168 + c * 64 + b];
                z[g] = rs * (zG - m * s1p[pcb + g]) + zb1p[pcb + g] + zU;
            }
            float ig = sigf(z[0]), fg = sigf(z[1]), gg = tanhfast(z[2]), og = sigf(z[3]);
            int j = ntile * 4 + u, idx = gb * NU + j;
            float cn = fg * c1[idx] + ig * gg;
            c1[idx] = cn;
            h1[idx] = og * tanhfast(cn);
        }
        __syncthreads();  // protect SM (zex) from next iteration's staging writes
    }

    grid.sync();
    if (blk >= 128 && tid < 64) {
        ypass(h1, wf, bf, out, blk - 128, T_STEPS - 1, tid);
    }
}

// ---------------- launcher ----------------
extern "C" void kernel_launch(void* const* d_in, const int* in_sizes, int n_in,
                              void* d_out, int out_size, void* d_ws, size_t ws_size,
                              hipStream_t stream)
{
    const float* x     = (const float*)d_in[0];
    const float* w0    = (const float*)d_in[1];
    const float* u0    = (const float*)d_in[2];
    const float* b0    = (const float*)d_in[3];
    const float* gamma = (const float*)d_in[4];
    const float* beta  = (const float*)d_in[5];
    const float* w1    = (const float*)d_in[6];
    const float* u1    = (const float*)d_in[7];
    const float* b1    = (const float*)d_in[8];
    const float* wf    = (const float*)d_in[9];
    const float* bf    = (const float*)d_in[10];
    float* out = (float*)d_out;
    float* ws  = (float*)d_ws;

    hipLaunchKernelGGL(pack0_kernel, dim3(128 * 10), dim3(256), 0, stream, w0, u0, ws + OFF_BP0);
    hipLaunchKernelGGL(pack1_kernel, dim3(128 * 16), dim3(256), 0, stream, w1, u1, gamma, ws + OFF_BP1);
    hipLaunchKernelGGL(sums_kernel, dim3(8), dim3(256), 0, stream,
                       w1, gamma, beta, b0, b1, ws + OFF_S1P, ws + OFF_ZB1P, ws + OFF_B0P);

    float* outp = out;
    float* wsp  = ws;
    const float* xp = x;
    const float* wfp = wf;
    const float* bfp = bf;
    void* args[] = { (void*)&xp, (void*)&wfp, (void*)&bfp, (void*)&wsp, (void*)&outp };
    hipLaunchCooperativeKernel((void*)lstm_main, dim3(256), dim3(512), args, 0, stream);
}